// Round 1
// baseline (9411.491 us; speedup 1.0000x reference)
//
#include <hip/hip_runtime.h>

#define TPB 256

__global__ __launch_bounds__(TPB) void k_deg_init(float* __restrict__ deg, int n) {
  int i = blockIdx.x * blockDim.x + threadIdx.x;
  if (i < n) deg[i] = 1.0f;  // self-loop
}

__global__ __launch_bounds__(TPB) void k_deg_count(const int* __restrict__ col,
                                                   float* __restrict__ deg, int e) {
  int i = blockIdx.x * blockDim.x + threadIdx.x;
  if (i < e) atomicAdd(&deg[col[i]], 1.0f);
}

__global__ __launch_bounds__(TPB) void k_dinv(float* __restrict__ d, int n) {
  int i = blockIdx.x * blockDim.x + threadIdx.x;
  if (i < n) d[i] = rsqrtf(d[i]);  // deg >= 1 always (self-loops)
}

// h1 = x @ W1 (128->4); also agg1_init = h1 * dinv^2 (self-loop message).
// 32 lanes per node, NPT nodes per lane-group; per-lane weights in VGPRs.
template <int NPT>
__global__ __launch_bounds__(TPB) void k_proj1(const float4* __restrict__ x4,
                                               const float4* __restrict__ W14,
                                               const float* __restrict__ dinv,
                                               float4* __restrict__ h1,
                                               float4* __restrict__ agg1, int n) {
  int tid = blockIdx.x * blockDim.x + threadIdx.x;
  int group = tid >> 5;
  int lane = tid & 31;
  // lane covers k = 4*lane .. 4*lane+3 ; W1 row k is float4 W14[k]
  float4 w0 = W14[lane * 4 + 0];
  float4 w1 = W14[lane * 4 + 1];
  float4 w2 = W14[lane * 4 + 2];
  float4 w3 = W14[lane * 4 + 3];
  int node0 = group * NPT;
#pragma unroll
  for (int t = 0; t < NPT; ++t) {
    int node = node0 + t;
    if (node >= n) return;
    float4 v = x4[(size_t)node * 32 + lane];
    float a0 = v.x * w0.x + v.y * w1.x + v.z * w2.x + v.w * w3.x;
    float a1 = v.x * w0.y + v.y * w1.y + v.z * w2.y + v.w * w3.y;
    float a2 = v.x * w0.z + v.y * w1.z + v.z * w2.z + v.w * w3.z;
    float a3 = v.x * w0.w + v.y * w1.w + v.z * w2.w + v.w * w3.w;
#pragma unroll
    for (int off = 16; off >= 1; off >>= 1) {
      a0 += __shfl_xor(a0, off, 32);
      a1 += __shfl_xor(a1, off, 32);
      a2 += __shfl_xor(a2, off, 32);
      a3 += __shfl_xor(a3, off, 32);
    }
    if (lane == 0) {
      h1[node] = make_float4(a0, a1, a2, a3);
    } else if (lane == 1) {
      float di = dinv[node];
      float s = di * di;
      agg1[node] = make_float4(a0 * s, a1 * s, a2 * s, a3 * s);
    }
  }
}

// edge scatter: agg[col] += h[row] * dinv[row]*dinv[col], d=4
__global__ __launch_bounds__(TPB) void k_agg4(const int* __restrict__ row,
                                              const int* __restrict__ col,
                                              const float* __restrict__ dinv,
                                              const float4* __restrict__ h,
                                              float* __restrict__ agg, int e) {
  int i = blockIdx.x * blockDim.x + threadIdx.x;
  if (i >= e) return;
  int r = row[i], c = col[i];
  float w = dinv[r] * dinv[c];
  float4 v = h[r];
  float* p = agg + (size_t)c * 4;
  atomicAdd(p + 0, v.x * w);
  atomicAdd(p + 1, v.y * w);
  atomicAdd(p + 2, v.z * w);
  atomicAdd(p + 3, v.w * w);
}

// edge scatter, d=2
__global__ __launch_bounds__(TPB) void k_agg2(const int* __restrict__ row,
                                              const int* __restrict__ col,
                                              const float* __restrict__ dinv,
                                              const float2* __restrict__ h,
                                              float* __restrict__ agg, int e) {
  int i = blockIdx.x * blockDim.x + threadIdx.x;
  if (i >= e) return;
  int r = row[i], c = col[i];
  float w = dinv[r] * dinv[c];
  float2 v = h[r];
  float* p = agg + (size_t)c * 2;
  atomicAdd(p + 0, v.x * w);
  atomicAdd(p + 1, v.y * w);
}

// t = tanh(agg1+b1); h2 = t @ W2 (4->4); agg2_init = h2 * dinv^2 (in-place over agg1)
__global__ __launch_bounds__(TPB) void k_fin1(const float4* __restrict__ agg1,
                                              const float* __restrict__ b1,
                                              const float4* __restrict__ W24,
                                              const float* __restrict__ dinv,
                                              float4* __restrict__ h2,
                                              float4* __restrict__ agg2, int n) {
  int i = blockIdx.x * blockDim.x + threadIdx.x;
  if (i >= n) return;
  float4 a = agg1[i];
  float t0 = tanhf(a.x + b1[0]);
  float t1 = tanhf(a.y + b1[1]);
  float t2 = tanhf(a.z + b1[2]);
  float t3 = tanhf(a.w + b1[3]);
  float4 r0 = W24[0], r1 = W24[1], r2 = W24[2], r3 = W24[3];
  float4 o;
  o.x = t0 * r0.x + t1 * r1.x + t2 * r2.x + t3 * r3.x;
  o.y = t0 * r0.y + t1 * r1.y + t2 * r2.y + t3 * r3.y;
  o.z = t0 * r0.z + t1 * r1.z + t2 * r2.z + t3 * r3.z;
  o.w = t0 * r0.w + t1 * r1.w + t2 * r2.w + t3 * r3.w;
  h2[i] = o;
  float di = dinv[i];
  float s = di * di;
  agg2[i] = make_float4(o.x * s, o.y * s, o.z * s, o.w * s);
}

// t = tanh(agg2+b2); h3 = t @ W3 (4->2); agg3_init = h3 * dinv^2
__global__ __launch_bounds__(TPB) void k_fin2(const float4* __restrict__ agg2,
                                              const float* __restrict__ b2,
                                              const float4* __restrict__ W34,
                                              const float* __restrict__ dinv,
                                              float2* __restrict__ h3,
                                              float2* __restrict__ agg3, int n) {
  int i = blockIdx.x * blockDim.x + threadIdx.x;
  if (i >= n) return;
  float4 a = agg2[i];
  float t0 = tanhf(a.x + b2[0]);
  float t1 = tanhf(a.y + b2[1]);
  float t2 = tanhf(a.z + b2[2]);
  float t3 = tanhf(a.w + b2[3]);
  float4 wA = W34[0];  // W3[0][0],W3[0][1],W3[1][0],W3[1][1]
  float4 wB = W34[1];  // W3[2][0],W3[2][1],W3[3][0],W3[3][1]
  float o0 = t0 * wA.x + t1 * wA.z + t2 * wB.x + t3 * wB.z;
  float o1 = t0 * wA.y + t1 * wA.w + t2 * wB.y + t3 * wB.w;
  h3[i] = make_float2(o0, o1);
  float di = dinv[i];
  float s = di * di;
  agg3[i] = make_float2(o0 * s, o1 * s);
}

// t = tanh(agg3+b3); out = t @ Wc + bc (2->16); hout = t
__global__ __launch_bounds__(TPB) void k_fin3(const float2* __restrict__ agg3,
                                              const float* __restrict__ b3,
                                              const float4* __restrict__ Wc4,
                                              const float4* __restrict__ bc4,
                                              float* __restrict__ out,
                                              float2* __restrict__ hout, int n) {
  int i = blockIdx.x * blockDim.x + threadIdx.x;
  if (i >= n) return;
  float2 a = agg3[i];
  float t0 = tanhf(a.x + b3[0]);
  float t1 = tanhf(a.y + b3[1]);
  float4* o4 = (float4*)(out + (size_t)i * 16);
#pragma unroll
  for (int m = 0; m < 4; ++m) {
    float4 w0 = Wc4[m];      // Wc row 0, cols 4m..4m+3
    float4 w1 = Wc4[4 + m];  // Wc row 1
    float4 bb = bc4[m];
    float4 o;
    o.x = t0 * w0.x + t1 * w1.x + bb.x;
    o.y = t0 * w0.y + t1 * w1.y + bb.y;
    o.z = t0 * w0.z + t1 * w1.z + bb.z;
    o.w = t0 * w0.w + t1 * w1.w + bb.w;
    o4[m] = o;
  }
  hout[i] = make_float2(t0, t1);
}

extern "C" void kernel_launch(void* const* d_in, const int* in_sizes, int n_in,
                              void* d_out, int out_size, void* d_ws, size_t ws_size,
                              hipStream_t stream) {
  const float* x  = (const float*)d_in[0];
  const int*  ei  = (const int*)d_in[1];
  const float* W1 = (const float*)d_in[2];
  const float* b1 = (const float*)d_in[3];
  const float* W2 = (const float*)d_in[4];
  const float* b2 = (const float*)d_in[5];
  const float* W3 = (const float*)d_in[6];
  const float* b3 = (const float*)d_in[7];
  const float* Wc = (const float*)d_in[8];
  const float* bc = (const float*)d_in[9];

  const int n = in_sizes[0] / 128;
  const int e = in_sizes[1] / 2;
  const int* row = ei;       // sources
  const int* col = ei + e;   // targets

  // workspace: dinv (4n B) | bufA (16n B) | bufB (16n B)
  char* ws = (char*)d_ws;
  size_t off0 = 0;
  size_t offA = (off0 + (size_t)n * 4 + 255) / 256 * 256;
  size_t offB = (offA + (size_t)n * 16 + 255) / 256 * 256;
  float* dinv = (float*)(ws + off0);
  float* bufA = (float*)(ws + offA);
  float* bufB = (float*)(ws + offB);

  const int gb_n = (n + TPB - 1) / TPB;
  const int gb_e = (e + TPB - 1) / TPB;

  // degree / normalization
  k_deg_init<<<gb_n, TPB, 0, stream>>>(dinv, n);
  k_deg_count<<<gb_e, TPB, 0, stream>>>(col, dinv, e);
  k_dinv<<<gb_n, TPB, 0, stream>>>(dinv, n);

  // layer 1 projection (fused self-loop init): h1 -> bufA, agg1 -> bufB
  constexpr int NPT = 8;
  int groups = (n + NPT - 1) / NPT;
  int pblocks = (groups * 32 + TPB - 1) / TPB;
  k_proj1<NPT><<<pblocks, TPB, 0, stream>>>((const float4*)x, (const float4*)W1, dinv,
                                            (float4*)bufA, (float4*)bufB, n);
  // layer 1 propagate
  k_agg4<<<gb_e, TPB, 0, stream>>>(row, col, dinv, (const float4*)bufA, bufB, e);
  // layer 1 finish + layer 2 project (+ self-loop init): h2 -> bufA, agg2 -> bufB (in-place)
  k_fin1<<<gb_n, TPB, 0, stream>>>((const float4*)bufB, b1, (const float4*)W2, dinv,
                                   (float4*)bufA, (float4*)bufB, n);
  // layer 2 propagate
  k_agg4<<<gb_e, TPB, 0, stream>>>(row, col, dinv, (const float4*)bufA, bufB, e);
  // layer 2 finish + layer 3 project: h3 -> bufA[0,8n), agg3 -> bufA[8n,16n)
  float2* h3   = (float2*)bufA;
  float2* agg3 = (float2*)bufA + n;
  k_fin2<<<gb_n, TPB, 0, stream>>>((const float4*)bufB, b2, (const float4*)W3, dinv,
                                   h3, agg3, n);
  // layer 3 propagate
  k_agg2<<<gb_e, TPB, 0, stream>>>(row, col, dinv, (const float2*)h3, (float*)agg3, e);
  // layer 3 finish + classifier: out [n,16] then h [n,2] into d_out
  float* out_p = (float*)d_out;
  float2* h_p  = (float2*)((float*)d_out + (size_t)n * 16);
  k_fin3<<<gb_n, TPB, 0, stream>>>((const float2*)agg3, b3, (const float4*)Wc,
                                   (const float4*)bc, out_p, h_p, n);
}